// Round 1
// baseline (1700.339 us; speedup 1.0000x reference)
//
#include <hip/hip_runtime.h>

#define NN 100000   // nodes
#define NE 3200000  // edges
#define NF 128      // in features
#define NH 32       // hidden
#define NG 512      // graphs

// ---------------- init: deg = 1.0 (self loop) ----------------
__global__ void k_deg_init(float* __restrict__ deg) {
    int i = blockIdx.x * blockDim.x + threadIdx.x;
    if (i < NN) deg[i] = 1.0f;
}

// ---------------- deg accumulation over edge dst ----------------
__global__ void k_deg(const int* __restrict__ dst, float* __restrict__ deg) {
    int i = blockIdx.x * blockDim.x + threadIdx.x;  // one thread = 4 edges
    if (i * 4 >= NE) return;
    int4 d = ((const int4*)dst)[i];
    atomicAdd(&deg[d.x], 1.0f);
    atomicAdd(&deg[d.y], 1.0f);
    atomicAdd(&deg[d.z], 1.0f);
    atomicAdd(&deg[d.w], 1.0f);
}

// ---------------- hs = (x @ W1) * rsqrt(deg[row]) ----------------
// block = 256 threads, 32 rows/block. W1 (128x32) and x-tile staged in LDS.
__global__ __launch_bounds__(256) void k_gemm(const float* __restrict__ x,
                                              const float* __restrict__ W1,
                                              const float* __restrict__ deg,
                                              float* __restrict__ hs) {
    __shared__ float sW[NF][NH];        // 16 KB
    __shared__ float sX[32][NF + 4];    // pad 128->132 floats: no bank conflict
    int t = threadIdx.x;
    const float4* W4 = (const float4*)W1;
    float4* sW4 = (float4*)&sW[0][0];
#pragma unroll
    for (int i = 0; i < 4; ++i) sW4[t + 256 * i] = W4[t + 256 * i];

    long row0 = (long)blockIdx.x * 32;
    const float4* x4 = (const float4*)(x + row0 * NF);
#pragma unroll
    for (int i = 0; i < 4; ++i) {
        int idx4 = t + 256 * i;          // float4 index within 32x128 tile
        int r = idx4 >> 5;               // 32 float4 per row
        int c = (idx4 & 31) * 4;
        float4 v = x4[idx4];
        sX[r][c] = v.x; sX[r][c + 1] = v.y; sX[r][c + 2] = v.z; sX[r][c + 3] = v.w;
    }
    __syncthreads();

    int r = t >> 3;
    int c = (t & 7) * 4;
    float4 acc = {0.f, 0.f, 0.f, 0.f};
#pragma unroll 8
    for (int k = 0; k < NF; ++k) {
        float xv = sX[r][k];
        float4 w = *(const float4*)&sW[k][c];
        acc.x += xv * w.x; acc.y += xv * w.y;
        acc.z += xv * w.z; acc.w += xv * w.w;
    }
    float dinv = rsqrtf(deg[row0 + r]);
    acc.x *= dinv; acc.y *= dinv; acc.z *= dinv; acc.w *= dinv;
    *(float4*)&hs[(row0 + r) * NH + c] = acc;
}

// ---------------- scatter: acc[dst] += hs[src], 8 threads/edge ----------------
__global__ __launch_bounds__(256) void k_scatter(const int* __restrict__ src,
                                                 const int* __restrict__ dst,
                                                 const float* __restrict__ hs,
                                                 float* __restrict__ acc) {
    int tid = blockIdx.x * blockDim.x + threadIdx.x;
    int e = tid >> 3;
    if (e >= NE) return;
    int cg = (tid & 7) * 4;
    int u = src[e];
    int v = dst[e];
    float4 m = *(const float4*)&hs[(size_t)u * NH + cg];
    float* a = &acc[(size_t)v * NH + cg];
    atomicAdd(a + 0, m.x);
    atomicAdd(a + 1, m.y);
    atomicAdd(a + 2, m.z);
    atomicAdd(a + 3, m.w);
}

// ---------------- finalize node + pooled reductions ----------------
__global__ __launch_bounds__(256) void k_pool(const float* __restrict__ hs,
                                              const float* __restrict__ acc,
                                              const float* __restrict__ deg,
                                              const float* __restrict__ b1,
                                              const int* __restrict__ batch,
                                              float* __restrict__ s,
                                              unsigned int* __restrict__ mx,
                                              float* __restrict__ cnt) {
    int tid = blockIdx.x * blockDim.x + threadIdx.x;
    int v = tid >> 3;
    if (v >= NN) return;
    int cg = (tid & 7) * 4;
    float dinv = rsqrtf(deg[v]);
    float4 a = *(const float4*)&acc[(size_t)v * NH + cg];
    float4 h = *(const float4*)&hs[(size_t)v * NH + cg];
    float4 bb = *(const float4*)&b1[cg];
    float r0 = fmaxf((a.x + h.x) * dinv + bb.x, 0.0f);
    float r1 = fmaxf((a.y + h.y) * dinv + bb.y, 0.0f);
    float r2 = fmaxf((a.z + h.z) * dinv + bb.z, 0.0f);
    float r3 = fmaxf((a.w + h.w) * dinv + bb.w, 0.0f);
    int b = batch[v];
    float* sp = s + (size_t)b * NH + cg;
    atomicAdd(sp + 0, r0); atomicAdd(sp + 1, r1);
    atomicAdd(sp + 2, r2); atomicAdd(sp + 3, r3);
    unsigned int* mp = mx + (size_t)b * NH + cg;
    atomicMax(mp + 0, __float_as_uint(r0));  // post-relu >= 0: uint order == float order
    atomicMax(mp + 1, __float_as_uint(r1));
    atomicMax(mp + 2, __float_as_uint(r2));
    atomicMax(mp + 3, __float_as_uint(r3));
    if ((tid & 7) == 0) atomicAdd(&cnt[b], 1.0f);
}

// ---------------- head: out[g] = [s, s/cnt, mx] @ Wg + bg ----------------
__global__ void k_head(const float* __restrict__ s,
                       const unsigned int* __restrict__ mx,
                       const float* __restrict__ cnt,
                       const float* __restrict__ Wg,
                       const float* __restrict__ bg,
                       float* __restrict__ out) {
    int g = blockIdx.x * blockDim.x + threadIdx.x;
    if (g >= NG) return;
    float inv = 1.0f / fmaxf(cnt[g], 1.0f);
    float accv = bg[0];
#pragma unroll 4
    for (int k = 0; k < NH; ++k) {
        float sv = s[g * NH + k];
        float mv = __uint_as_float(mx[g * NH + k]);
        accv += sv * Wg[k] + sv * inv * Wg[NH + k] + mv * Wg[2 * NH + k];
    }
    out[g] = accv;
}

extern "C" void kernel_launch(void* const* d_in, const int* in_sizes, int n_in,
                              void* d_out, int out_size, void* d_ws, size_t ws_size,
                              hipStream_t stream) {
    const float* x     = (const float*)d_in[0];
    const int*   ei    = (const int*)d_in[1];
    const int*   batch = (const int*)d_in[2];
    const float* W1    = (const float*)d_in[3];
    const float* b1    = (const float*)d_in[4];
    const float* Wg    = (const float*)d_in[5];
    const float* bg    = (const float*)d_in[6];
    float* out = (float*)d_out;

    const int* src = ei;        // edge_index[0]
    const int* dst = ei + NE;   // edge_index[1]

    // workspace layout (bytes), all offsets 16B-aligned
    char* ws = (char*)d_ws;
    float*        deg  = (float*)(ws + 0);          // N floats        (400000 B)
    float*        hs   = (float*)(ws + 400000);     // N*32 floats     (12.8 MB)
    float*        accb = (float*)(ws + 13200000);   // N*32 floats     (12.8 MB)
    float*        s    = (float*)(ws + 26000000);   // G*32 floats
    unsigned int* mx   = (unsigned int*)(ws + 26065536);  // G*32 uints
    float*        cnt  = (float*)(ws + 26131072);   // G floats

    // zero accumulators every call (harness does not re-poison between replays)
    hipMemsetAsync(accb, 0, (size_t)NN * NH * sizeof(float), stream);
    hipMemsetAsync(s, 0, (size_t)NG * NH * sizeof(float), stream);
    hipMemsetAsync(mx, 0, (size_t)NG * NH * sizeof(unsigned int), stream);
    hipMemsetAsync(cnt, 0, (size_t)NG * sizeof(float), stream);

    k_deg_init<<<(NN + 255) / 256, 256, 0, stream>>>(deg);
    k_deg<<<(NE / 4 + 255) / 256, 256, 0, stream>>>(dst, deg);
    k_gemm<<<NN / 32, 256, 0, stream>>>(x, W1, deg, hs);
    k_scatter<<<(NE * 8) / 256, 256, 0, stream>>>(src, dst, hs, accb);
    k_pool<<<(NN * 8) / 256, 256, 0, stream>>>(hs, accb, deg, b1, batch, s, mx, cnt);
    k_head<<<(NG + 255) / 256, 256, 0, stream>>>(s, mx, cnt, Wg, bg, out);
}

// Round 6
// 903.008 us; speedup vs baseline: 1.8830x; 1.8830x over previous
//
#include <hip/hip_runtime.h>

#define NN 100000   // nodes
#define NE 3200000  // edges
#define NF 128      // in features
#define NH 32       // hidden
#define NG 512      // graphs
#define SCAN_T 1024

// ---------------- histogram: cnt_i[v] = in-degree (edges only) ----------------
__global__ void k_count(const int* __restrict__ dst, int* __restrict__ cnt_i) {
    int i = blockIdx.x * blockDim.x + threadIdx.x;  // one thread = 4 edges
    if (i * 4 >= NE) return;
    int4 d = ((const int4*)dst)[i];
    atomicAdd(&cnt_i[d.x], 1);
    atomicAdd(&cnt_i[d.y], 1);
    atomicAdd(&cnt_i[d.z], 1);
    atomicAdd(&cnt_i[d.w], 1);
}

// ---------------- single-block exclusive scan -> row_ptr, cursor, dinv ----------------
__global__ __launch_bounds__(SCAN_T) void k_scan(const int* __restrict__ cnt_i,
                                                 int* __restrict__ row_ptr,
                                                 int* __restrict__ cursor,
                                                 float* __restrict__ dinv) {
    const int C = (NN + SCAN_T - 1) / SCAN_T;  // 98
    int t = threadIdx.x;
    int beg = t * C;
    int end = beg + C; if (end > NN) end = NN;
    int sum = 0;
    for (int i = beg; i < end; ++i) sum += cnt_i[i];
    __shared__ int part[SCAN_T];
    part[t] = sum;
    __syncthreads();
    for (int off = 1; off < SCAN_T; off <<= 1) {   // Hillis-Steele inclusive scan
        int v = (t >= off) ? part[t - off] : 0;
        __syncthreads();
        part[t] += v;
        __syncthreads();
    }
    int run = part[t] - sum;  // exclusive prefix of this chunk
    for (int i = beg; i < end; ++i) {
        int c = cnt_i[i];
        row_ptr[i] = run;
        cursor[i] = run;
        dinv[i] = rsqrtf((float)(c + 1));  // +1 self-loop
        run += c;
    }
    if (t == SCAN_T - 1) row_ptr[NN] = run;  // == NE
}

// ---------------- bucket fill: CSR column indices (src per dst) ----------------
__global__ __launch_bounds__(256) void k_fill(const int* __restrict__ src,
                                              const int* __restrict__ dst,
                                              int* __restrict__ cursor,
                                              int* __restrict__ bucket) {
    int e = blockIdx.x * blockDim.x + threadIdx.x;
    if (e >= NE) return;
    int p = atomicAdd(&cursor[dst[e]], 1);
    bucket[p] = src[e];
}

// ---------------- hs = (x @ W1) * dinv[row] ----------------
__global__ __launch_bounds__(256) void k_gemm(const float* __restrict__ x,
                                              const float* __restrict__ W1,
                                              const float* __restrict__ dinv,
                                              float* __restrict__ hs) {
    __shared__ float sW[NF][NH];        // 16 KB
    __shared__ float sX[32][NF + 4];    // padded: no bank conflict
    int t = threadIdx.x;
    const float4* W4 = (const float4*)W1;
    float4* sW4 = (float4*)&sW[0][0];
#pragma unroll
    for (int i = 0; i < 4; ++i) sW4[t + 256 * i] = W4[t + 256 * i];

    long row0 = (long)blockIdx.x * 32;
    const float4* x4 = (const float4*)(x + row0 * NF);
#pragma unroll
    for (int i = 0; i < 4; ++i) {
        int idx4 = t + 256 * i;
        int r = idx4 >> 5;
        int c = (idx4 & 31) * 4;
        float4 v = x4[idx4];
        sX[r][c] = v.x; sX[r][c + 1] = v.y; sX[r][c + 2] = v.z; sX[r][c + 3] = v.w;
    }
    __syncthreads();

    int r = t >> 3;
    int c = (t & 7) * 4;
    float4 acc = {0.f, 0.f, 0.f, 0.f};
#pragma unroll 8
    for (int k = 0; k < NF; ++k) {
        float xv = sX[r][k];
        float4 w = *(const float4*)&sW[k][c];
        acc.x += xv * w.x; acc.y += xv * w.y;
        acc.z += xv * w.z; acc.w += xv * w.w;
    }
    float dv = dinv[row0 + r];
    acc.x *= dv; acc.y *= dv; acc.z *= dv; acc.w *= dv;
    *(float4*)&hs[(row0 + r) * NH + c] = acc;
}

// ---------------- gather + finalize + fused pooling ----------------
// 1 wave per node (4 nodes/block). lane = j*32+f: j in {0,1} edges, f feature.
__global__ __launch_bounds__(256) void k_gather_pool(
    const int* __restrict__ row_ptr, const int* __restrict__ bucket,
    const float* __restrict__ hs, const float* __restrict__ dinv,
    const float* __restrict__ b1, const int* __restrict__ batch,
    float* __restrict__ s, unsigned int* __restrict__ mx, float* __restrict__ cnt) {
    __shared__ float sv[4][NH];
    __shared__ int sg[4];
    int wave = threadIdx.x >> 6;
    int lane = threadIdx.x & 63;
    int f = lane & 31;
    int j = lane >> 5;
    int v = blockIdx.x * 4 + wave;  // NN % 4 == 0: exact
    int beg = row_ptr[v], end = row_ptr[v + 1];
    float acc = 0.f;
    for (int i = beg + j; i < end; i += 2) {
        int u = bucket[i];                 // broadcast within half-wave
        acc += hs[(size_t)u * NH + f];     // 128B contiguous per half-wave
    }
    acc += __shfl_xor(acc, 32);            // combine j=0/1
    if (j == 0) {
        float r = fmaxf((acc + hs[(size_t)v * NH + f]) * dinv[v] + b1[f], 0.f);
        sv[wave][f] = r;
        if (f == 0) sg[wave] = batch[v];
    }
    __syncthreads();
    if (threadIdx.x < NH) {  // run-flush 4 consecutive nodes (batch sorted)
        int ff = threadIdx.x;
        int curg = sg[0];
        float rs = 0.f, rm = 0.f, rc = 0.f;
#pragma unroll
        for (int k = 0; k < 4; ++k) {
            int g = sg[k];
            float val = sv[k][ff];
            if (g != curg) {
                atomicAdd(&s[curg * NH + ff], rs);
                atomicMax(&mx[curg * NH + ff], __float_as_uint(rm));
                if (ff == 0) atomicAdd(&cnt[curg], rc);
                curg = g; rs = 0.f; rm = 0.f; rc = 0.f;
            }
            rs += val; rm = fmaxf(rm, val); rc += 1.f;
        }
        atomicAdd(&s[curg * NH + ff], rs);
        atomicMax(&mx[curg * NH + ff], __float_as_uint(rm));  // post-relu >= 0
        if (ff == 0) atomicAdd(&cnt[curg], rc);
    }
}

// ---------------- head: out[g] = [s, s/cnt, mx] @ Wg + bg ----------------
__global__ void k_head(const float* __restrict__ s,
                       const unsigned int* __restrict__ mx,
                       const float* __restrict__ cnt,
                       const float* __restrict__ Wg,
                       const float* __restrict__ bg,
                       float* __restrict__ out) {
    int g = blockIdx.x * blockDim.x + threadIdx.x;
    if (g >= NG) return;
    float inv = 1.0f / fmaxf(cnt[g], 1.0f);
    float accv = bg[0];
#pragma unroll 4
    for (int k = 0; k < NH; ++k) {
        float sv = s[g * NH + k];
        float mv = __uint_as_float(mx[g * NH + k]);
        accv += sv * Wg[k] + sv * inv * Wg[NH + k] + mv * Wg[2 * NH + k];
    }
    out[g] = accv;
}

extern "C" void kernel_launch(void* const* d_in, const int* in_sizes, int n_in,
                              void* d_out, int out_size, void* d_ws, size_t ws_size,
                              hipStream_t stream) {
    const float* x     = (const float*)d_in[0];
    const int*   ei    = (const int*)d_in[1];
    const int*   batch = (const int*)d_in[2];
    const float* W1    = (const float*)d_in[3];
    const float* b1    = (const float*)d_in[4];
    const float* Wg    = (const float*)d_in[5];
    const float* bg    = (const float*)d_in[6];
    float* out = (float*)d_out;

    const int* src = ei;        // edge_index[0]
    const int* dst = ei + NE;   // edge_index[1]

    // workspace layout (16B-aligned offsets)
    char* ws = (char*)d_ws;
    int*          cnt_i   = (int*)(ws + 0);         // NN
    int*          row_ptr = (int*)(ws + 400000);    // NN+1 (padded to 400016)
    int*          cursor  = (int*)(ws + 800016);    // NN
    float*        dinv    = (float*)(ws + 1200016); // NN
    int*          bucket  = (int*)(ws + 1600016);   // NE
    float*        hs      = (float*)(ws + 14400016);// NN*NH
    float*        s       = (float*)(ws + 27200016);// NG*NH
    unsigned int* mx      = (unsigned int*)(ws + 27265552);
    float*        cnt     = (float*)(ws + 27331088);// NG
    // total 27,333,136 B

    hipMemsetAsync(cnt_i, 0, (size_t)NN * sizeof(int), stream);
    hipMemsetAsync(s, 0, (size_t)NG * NH * sizeof(float), stream);
    hipMemsetAsync(mx, 0, (size_t)NG * NH * sizeof(unsigned int), stream);
    hipMemsetAsync(cnt, 0, (size_t)NG * sizeof(float), stream);

    k_count<<<(NE / 4 + 255) / 256, 256, 0, stream>>>(dst, cnt_i);
    k_scan<<<1, SCAN_T, 0, stream>>>(cnt_i, row_ptr, cursor, dinv);
    k_fill<<<(NE + 255) / 256, 256, 0, stream>>>(src, dst, cursor, bucket);
    k_gemm<<<NN / 32, 256, 0, stream>>>(x, W1, dinv, hs);
    k_gather_pool<<<NN / 4, 256, 0, stream>>>(row_ptr, bucket, hs, dinv, b1, batch,
                                              s, mx, cnt);
    k_head<<<(NG + 255) / 256, 256, 0, stream>>>(s, mx, cnt, Wg, bg, out);
}

// Round 7
// 550.977 us; speedup vs baseline: 3.0860x; 1.6389x over previous
//
#include <hip/hip_runtime.h>

#define NN 100000   // nodes
#define NE 3200000  // edges
#define NF 128      // in features
#define NH 32       // hidden
#define NG 512      // graphs
#define NBLK 391    // ceil(NN/256) scan blocks

// ---------------- histogram: cnt_i[v] = in-degree (edges only) ----------------
__global__ void k_count(const int* __restrict__ dst, int* __restrict__ cnt_i) {
    int i = blockIdx.x * blockDim.x + threadIdx.x;  // one thread = 4 edges
    if (i * 4 >= NE) return;
    int4 d = ((const int4*)dst)[i];
    atomicAdd(&cnt_i[d.x], 1);
    atomicAdd(&cnt_i[d.y], 1);
    atomicAdd(&cnt_i[d.z], 1);
    atomicAdd(&cnt_i[d.w], 1);
}

// ---------------- scan stage 1: per-block sums of cnt_i ----------------
__global__ __launch_bounds__(256) void k_blocksum(const int* __restrict__ cnt_i,
                                                  int* __restrict__ bsum) {
    int t = threadIdx.x;
    int i = blockIdx.x * 256 + t;
    int c = (i < NN) ? cnt_i[i] : 0;
    // wave reduce (64 lanes)
    for (int m = 1; m < 64; m <<= 1) c += __shfl_xor(c, m);
    __shared__ int wsum[4];
    if ((t & 63) == 0) wsum[t >> 6] = c;
    __syncthreads();
    if (t == 0) bsum[blockIdx.x] = wsum[0] + wsum[1] + wsum[2] + wsum[3];
}

// ---------------- scan stage 2: 1-block exclusive scan of 391 block sums ----------------
__global__ __launch_bounds__(512) void k_scan_bsum(const int* __restrict__ bsum,
                                                   int* __restrict__ boff) {
    int t = threadIdx.x;
    int own = (t < NBLK) ? bsum[t] : 0;
    __shared__ int part[512];
    part[t] = own;
    __syncthreads();
    for (int off = 1; off < 512; off <<= 1) {
        int v = (t >= off) ? part[t - off] : 0;
        __syncthreads();
        part[t] += v;
        __syncthreads();
    }
    if (t < NBLK) boff[t] = part[t] - own;  // exclusive
}

// ---------------- scan stage 3: intra-block rescan + row_ptr/cursor/dinv ----------------
__global__ __launch_bounds__(256) void k_scan_final(const int* __restrict__ cnt_i,
                                                    const int* __restrict__ boff,
                                                    int* __restrict__ row_ptr,
                                                    int* __restrict__ cursor,
                                                    float* __restrict__ dinv) {
    int t = threadIdx.x;
    int i = blockIdx.x * 256 + t;
    int c = (i < NN) ? cnt_i[i] : 0;
    __shared__ int part[256];
    part[t] = c;
    __syncthreads();
    for (int off = 1; off < 256; off <<= 1) {
        int v = (t >= off) ? part[t - off] : 0;
        __syncthreads();
        part[t] += v;
        __syncthreads();
    }
    if (i < NN) {
        int p = boff[blockIdx.x] + part[t] - c;  // exclusive prefix
        row_ptr[i] = p;
        cursor[i] = p;
        dinv[i] = rsqrtf((float)(c + 1));  // +1 self-loop
    }
    if (blockIdx.x == 0 && t == 0) row_ptr[NN] = NE;  // total = all edges
}

// ---------------- bucket fill: CSR column indices (src per dst) ----------------
__global__ __launch_bounds__(256) void k_fill(const int* __restrict__ src,
                                              const int* __restrict__ dst,
                                              int* __restrict__ cursor,
                                              int* __restrict__ bucket) {
    int i = blockIdx.x * blockDim.x + threadIdx.x;  // one thread = 4 edges
    if (i * 4 >= NE) return;
    int4 d = ((const int4*)dst)[i];
    int4 sv = ((const int4*)src)[i];
    int p;
    p = atomicAdd(&cursor[d.x], 1); bucket[p] = sv.x;
    p = atomicAdd(&cursor[d.y], 1); bucket[p] = sv.y;
    p = atomicAdd(&cursor[d.z], 1); bucket[p] = sv.z;
    p = atomicAdd(&cursor[d.w], 1); bucket[p] = sv.w;
}

// ---------------- hs = (x @ W1) * dinv[row] ----------------
__global__ __launch_bounds__(256) void k_gemm(const float* __restrict__ x,
                                              const float* __restrict__ W1,
                                              const float* __restrict__ dinv,
                                              float* __restrict__ hs) {
    __shared__ float sW[NF][NH];        // 16 KB
    __shared__ float sX[32][NF + 4];    // padded: no bank conflict
    int t = threadIdx.x;
    const float4* W4 = (const float4*)W1;
    float4* sW4 = (float4*)&sW[0][0];
#pragma unroll
    for (int i = 0; i < 4; ++i) sW4[t + 256 * i] = W4[t + 256 * i];

    long row0 = (long)blockIdx.x * 32;
    const float4* x4 = (const float4*)(x + row0 * NF);
#pragma unroll
    for (int i = 0; i < 4; ++i) {
        int idx4 = t + 256 * i;
        int r = idx4 >> 5;
        int c = (idx4 & 31) * 4;
        float4 v = x4[idx4];
        sX[r][c] = v.x; sX[r][c + 1] = v.y; sX[r][c + 2] = v.z; sX[r][c + 3] = v.w;
    }
    __syncthreads();

    int r = t >> 3;
    int c = (t & 7) * 4;
    float4 acc = {0.f, 0.f, 0.f, 0.f};
#pragma unroll 8
    for (int k = 0; k < NF; ++k) {
        float xv = sX[r][k];
        float4 w = *(const float4*)&sW[k][c];
        acc.x += xv * w.x; acc.y += xv * w.y;
        acc.z += xv * w.z; acc.w += xv * w.w;
    }
    float dv = dinv[row0 + r];
    acc.x *= dv; acc.y *= dv; acc.z *= dv; acc.w *= dv;
    *(float4*)&hs[(row0 + r) * NH + c] = acc;
}

// ---------------- gather + finalize + fused pooling ----------------
// 1 wave per node (4 nodes/block). lane = es*8 + fq: es in [0,8) edge slots,
// fq in [0,8) float4 feature quads -> 8 edges x 16B in flight per iteration.
__global__ __launch_bounds__(256) void k_gather_pool(
    const int* __restrict__ row_ptr, const int* __restrict__ bucket,
    const float* __restrict__ hs, const float* __restrict__ dinv,
    const float* __restrict__ b1, const int* __restrict__ batch,
    float* __restrict__ s, unsigned int* __restrict__ mx, float* __restrict__ cnt) {
    __shared__ float sv[4][NH];
    __shared__ int sg[4];
    int wave = threadIdx.x >> 6;
    int lane = threadIdx.x & 63;
    int fq = lane & 7;        // float4 index: features 4*fq..4*fq+3
    int es = lane >> 3;       // edge slot 0..7
    int v = blockIdx.x * 4 + wave;  // NN % 4 == 0: exact
    int beg = row_ptr[v], end = row_ptr[v + 1];
    float4 acc = {0.f, 0.f, 0.f, 0.f};
    for (int i = beg + es; i < end; i += 8) {
        int u = bucket[i];                               // broadcast per 8-lane group
        float4 m = *(const float4*)&hs[(size_t)u * NH + fq * 4];  // 128B/edge coalesced
        acc.x += m.x; acc.y += m.y; acc.z += m.z; acc.w += m.w;
    }
#pragma unroll
    for (int m = 8; m < 64; m <<= 1) {  // reduce across es (3 steps)
        acc.x += __shfl_xor(acc.x, m);
        acc.y += __shfl_xor(acc.y, m);
        acc.z += __shfl_xor(acc.z, m);
        acc.w += __shfl_xor(acc.w, m);
    }
    if (es == 0) {
        float4 h = *(const float4*)&hs[(size_t)v * NH + fq * 4];
        float dv = dinv[v];
        float4 bb = *(const float4*)&b1[fq * 4];
        float4 r;
        r.x = fmaxf((acc.x + h.x) * dv + bb.x, 0.f);
        r.y = fmaxf((acc.y + h.y) * dv + bb.y, 0.f);
        r.z = fmaxf((acc.z + h.z) * dv + bb.z, 0.f);
        r.w = fmaxf((acc.w + h.w) * dv + bb.w, 0.f);
        *(float4*)&sv[wave][fq * 4] = r;
        if (fq == 0) sg[wave] = batch[v];
    }
    __syncthreads();
    if (threadIdx.x < NH) {  // run-flush 4 consecutive nodes (batch sorted)
        int ff = threadIdx.x;
        int curg = sg[0];
        float rs = 0.f, rm = 0.f, rc = 0.f;
#pragma unroll
        for (int k = 0; k < 4; ++k) {
            int g = sg[k];
            float val = sv[k][ff];
            if (g != curg) {
                atomicAdd(&s[curg * NH + ff], rs);
                atomicMax(&mx[curg * NH + ff], __float_as_uint(rm));
                if (ff == 0) atomicAdd(&cnt[curg], rc);
                curg = g; rs = 0.f; rm = 0.f; rc = 0.f;
            }
            rs += val; rm = fmaxf(rm, val); rc += 1.f;
        }
        atomicAdd(&s[curg * NH + ff], rs);
        atomicMax(&mx[curg * NH + ff], __float_as_uint(rm));  // post-relu >= 0
        if (ff == 0) atomicAdd(&cnt[curg], rc);
    }
}

// ---------------- head: out[g] = [s, s/cnt, mx] @ Wg + bg ----------------
__global__ void k_head(const float* __restrict__ s,
                       const unsigned int* __restrict__ mx,
                       const float* __restrict__ cnt,
                       const float* __restrict__ Wg,
                       const float* __restrict__ bg,
                       float* __restrict__ out) {
    int g = blockIdx.x * blockDim.x + threadIdx.x;
    if (g >= NG) return;
    float inv = 1.0f / fmaxf(cnt[g], 1.0f);
    float accv = bg[0];
#pragma unroll 4
    for (int k = 0; k < NH; ++k) {
        float sv = s[g * NH + k];
        float mv = __uint_as_float(mx[g * NH + k]);
        accv += sv * Wg[k] + sv * inv * Wg[NH + k] + mv * Wg[2 * NH + k];
    }
    out[g] = accv;
}

extern "C" void kernel_launch(void* const* d_in, const int* in_sizes, int n_in,
                              void* d_out, int out_size, void* d_ws, size_t ws_size,
                              hipStream_t stream) {
    const float* x     = (const float*)d_in[0];
    const int*   ei    = (const int*)d_in[1];
    const int*   batch = (const int*)d_in[2];
    const float* W1    = (const float*)d_in[3];
    const float* b1    = (const float*)d_in[4];
    const float* Wg    = (const float*)d_in[5];
    const float* bg    = (const float*)d_in[6];
    float* out = (float*)d_out;

    const int* src = ei;        // edge_index[0]
    const int* dst = ei + NE;   // edge_index[1]

    // workspace layout (16B-aligned offsets)
    char* ws = (char*)d_ws;
    int*          cnt_i   = (int*)(ws + 0);         // NN
    int*          row_ptr = (int*)(ws + 400000);    // NN+1
    int*          cursor  = (int*)(ws + 800016);    // NN
    float*        dinv    = (float*)(ws + 1200016); // NN
    int*          bucket  = (int*)(ws + 1600016);   // NE
    float*        hs      = (float*)(ws + 14400016);// NN*NH
    float*        s       = (float*)(ws + 27200016);// NG*NH
    unsigned int* mx      = (unsigned int*)(ws + 27265552);
    float*        cnt     = (float*)(ws + 27331088);// NG
    int*          bsum    = (int*)(ws + 27333136);  // NBLK
    int*          boff    = (int*)(ws + 27334704);  // NBLK
    // total ~27,336,268 B

    hipMemsetAsync(cnt_i, 0, (size_t)NN * sizeof(int), stream);
    hipMemsetAsync(s, 0, (size_t)NG * NH * sizeof(float), stream);
    hipMemsetAsync(mx, 0, (size_t)NG * NH * sizeof(unsigned int), stream);
    hipMemsetAsync(cnt, 0, (size_t)NG * sizeof(float), stream);

    k_count<<<(NE / 4 + 255) / 256, 256, 0, stream>>>(dst, cnt_i);
    k_blocksum<<<NBLK, 256, 0, stream>>>(cnt_i, bsum);
    k_scan_bsum<<<1, 512, 0, stream>>>(bsum, boff);
    k_scan_final<<<NBLK, 256, 0, stream>>>(cnt_i, boff, row_ptr, cursor, dinv);
    k_fill<<<(NE / 4 + 255) / 256, 256, 0, stream>>>(src, dst, cursor, bucket);
    k_gemm<<<NN / 32, 256, 0, stream>>>(x, W1, dinv, hs);
    k_gather_pool<<<NN / 4, 256, 0, stream>>>(row_ptr, bucket, hs, dinv, b1, batch,
                                              s, mx, cnt);
    k_head<<<(NG + 255) / 256, 256, 0, stream>>>(s, mx, cnt, Wg, bg, out);
}

// Round 9
// 251.278 us; speedup vs baseline: 6.7668x; 2.1927x over previous
//
#include <hip/hip_runtime.h>

#define NN 100000   // nodes
#define NE 3200000  // edges
#define NF 128      // in features
#define NH 32       // hidden
#define NG 512      // graphs
#define NR 782      // coarse ranges = ceil(NN/128)
#define RSZ 128     // nodes per range (dst>>7, dst&127)
#define EPB 4096    // edges per block in coarse passes
#define NBE 782     // ceil(NE/EPB)

// ---------------- C1: coarse histogram (LDS-privatized) ----------------
__global__ __launch_bounds__(256) void k_ccount(const int* __restrict__ dst,
                                                int* __restrict__ ccnt) {
    __shared__ int h[NR];
    for (int i = threadIdx.x; i < NR; i += 256) h[i] = 0;
    __syncthreads();
    int base = blockIdx.x * EPB;
    int lim = NE - base;
    const int4* d4 = (const int4*)(dst + base);
#pragma unroll
    for (int k = 0; k < 4; ++k) {
        int idx = threadIdx.x + k * 256;
        if (idx * 4 < lim) {
            int4 d = d4[idx];
            atomicAdd(&h[d.x >> 7], 1);
            atomicAdd(&h[d.y >> 7], 1);
            atomicAdd(&h[d.z >> 7], 1);
            atomicAdd(&h[d.w >> 7], 1);
        }
    }
    __syncthreads();
    for (int i = threadIdx.x; i < NR; i += 256) {
        int c = h[i];
        if (c) atomicAdd(&ccnt[i], c);
    }
}

// ---------------- C2: scan coarse counts -> cptr, ccur ----------------
__global__ __launch_bounds__(1024) void k_cscan(const int* __restrict__ ccnt,
                                                int* __restrict__ cptr,
                                                int* __restrict__ ccur) {
    int t = threadIdx.x;
    int own = (t < NR) ? ccnt[t] : 0;
    __shared__ int part[1024];
    part[t] = own;
    __syncthreads();
    for (int off = 1; off < 1024; off <<= 1) {
        int v = (t >= off) ? part[t - off] : 0;
        __syncthreads();
        part[t] += v;
        __syncthreads();
    }
    if (t < NR) { int ex = part[t] - own; cptr[t] = ex; ccur[t] = ex; }
    if (t == 0) cptr[NR] = NE;
}

// ---------------- C3: coarse scatter of packed (dstoff,src) words ----------------
__global__ __launch_bounds__(256) void k_cscatter(const int* __restrict__ src,
                                                  const int* __restrict__ dst,
                                                  int* __restrict__ ccur,
                                                  unsigned int* __restrict__ cbucket) {
    __shared__ int h[NR];
    __shared__ int basev[NR];
    for (int i = threadIdx.x; i < NR; i += 256) h[i] = 0;
    __syncthreads();
    int base = blockIdx.x * EPB;
    int lim = NE - base;
    const int4* d4 = (const int4*)(dst + base);
    const int4* s4 = (const int4*)(src + base);
    int4 dv[4], sv[4];
    int valid[4];
#pragma unroll
    for (int k = 0; k < 4; ++k) {
        int idx = threadIdx.x + k * 256;
        valid[k] = (idx * 4 < lim);
        if (valid[k]) {
            dv[k] = d4[idx];
            sv[k] = s4[idx];
            atomicAdd(&h[dv[k].x >> 7], 1);
            atomicAdd(&h[dv[k].y >> 7], 1);
            atomicAdd(&h[dv[k].z >> 7], 1);
            atomicAdd(&h[dv[k].w >> 7], 1);
        }
    }
    __syncthreads();
    for (int i = threadIdx.x; i < NR; i += 256) {   // reserve global bases
        int c = h[i];
        basev[i] = c ? atomicAdd(&ccur[i], c) : 0;
    }
    __syncthreads();
    for (int i = threadIdx.x; i < NR; i += 256) h[i] = 0;  // reuse as rank counters
    __syncthreads();
#pragma unroll
    for (int k = 0; k < 4; ++k) {
        if (valid[k]) {
            int d, s, r, p;
#define EMIT(DD, SS) d = (DD); s = (SS); r = d >> 7; \
            p = basev[r] + atomicAdd(&h[r], 1); \
            cbucket[p] = (unsigned int)(((d & 127) << 17) | s);
            EMIT(dv[k].x, sv[k].x)
            EMIT(dv[k].y, sv[k].y)
            EMIT(dv[k].z, sv[k].z)
            EMIT(dv[k].w, sv[k].w)
#undef EMIT
        }
    }
}

// ---------------- C4: per-range local sort -> bucket, row_ptr, dinv ----------------
__global__ __launch_bounds__(256) void k_rangesort(const int* __restrict__ cptr,
                                                   const unsigned int* __restrict__ cbucket,
                                                   int* __restrict__ row_ptr,
                                                   int* __restrict__ bucket,
                                                   float* __restrict__ dinv) {
    __shared__ int h[RSZ];
    __shared__ int lptr[RSZ];
    int r = blockIdx.x;
    int beg = cptr[r], end = cptr[r + 1];
    int t = threadIdx.x;
    if (t < RSZ) h[t] = 0;
    __syncthreads();
    for (int i = beg + t; i < end; i += 256)
        atomicAdd(&h[cbucket[i] >> 17], 1);
    __syncthreads();
    if (t < RSZ) lptr[t] = h[t];
    __syncthreads();
    for (int off = 1; off < RSZ; off <<= 1) {      // inclusive scan over 128
        int v = (t >= off && t < RSZ) ? lptr[t - off] : 0;
        __syncthreads();
        if (t < RSZ) lptr[t] += v;
        __syncthreads();
    }
    int node0 = r * RSZ;
    if (t < RSZ) {
        int v = node0 + t;
        if (v < NN) {
            int ex = lptr[t] - h[t];               // exclusive
            row_ptr[v] = beg + ex;
            dinv[v] = rsqrtf((float)(h[t] + 1));   // +1 self-loop
        }
    }
    __syncthreads();
    if (t < RSZ) h[t] = lptr[t] - h[t];            // reuse h as LDS cursor
    __syncthreads();
    for (int i = beg + t; i < end; i += 256) {
        unsigned int w = cbucket[i];
        int off_ = atomicAdd(&h[w >> 17], 1);
        bucket[beg + off_] = (int)(w & 0x1FFFF);
    }
    if (r == 0 && t == 0) row_ptr[NN] = NE;
}

// ---------------- hs = (x @ W1) * dinv[row] ----------------
__global__ __launch_bounds__(256) void k_gemm(const float* __restrict__ x,
                                              const float* __restrict__ W1,
                                              const float* __restrict__ dinv,
                                              float* __restrict__ hs) {
    __shared__ float sW[NF][NH];        // 16 KB
    __shared__ float sX[32][NF + 4];    // padded: no bank conflict
    int t = threadIdx.x;
    const float4* W4 = (const float4*)W1;
    float4* sW4 = (float4*)&sW[0][0];
#pragma unroll
    for (int i = 0; i < 4; ++i) sW4[t + 256 * i] = W4[t + 256 * i];

    long row0 = (long)blockIdx.x * 32;
    const float4* x4 = (const float4*)(x + row0 * NF);
#pragma unroll
    for (int i = 0; i < 4; ++i) {
        int idx4 = t + 256 * i;
        int r = idx4 >> 5;
        int c = (idx4 & 31) * 4;
        float4 v = x4[idx4];
        sX[r][c] = v.x; sX[r][c + 1] = v.y; sX[r][c + 2] = v.z; sX[r][c + 3] = v.w;
    }
    __syncthreads();

    int r = t >> 3;
    int c = (t & 7) * 4;
    float4 acc = {0.f, 0.f, 0.f, 0.f};
#pragma unroll 8
    for (int k = 0; k < NF; ++k) {
        float xv = sX[r][k];
        float4 w = *(const float4*)&sW[k][c];
        acc.x += xv * w.x; acc.y += xv * w.y;
        acc.z += xv * w.z; acc.w += xv * w.w;
    }
    float dv = dinv[row0 + r];
    acc.x *= dv; acc.y *= dv; acc.z *= dv; acc.w *= dv;
    *(float4*)&hs[(row0 + r) * NH + c] = acc;
}

// ---------------- gather + finalize + fused pooling ----------------
// 1 wave per node (4 nodes/block). lane = es*8 + fq: 8 edges x 16B in flight.
__global__ __launch_bounds__(256) void k_gather_pool(
    const int* __restrict__ row_ptr, const int* __restrict__ bucket,
    const float* __restrict__ hs, const float* __restrict__ dinv,
    const float* __restrict__ b1, const int* __restrict__ batch,
    float* __restrict__ s, unsigned int* __restrict__ mx, float* __restrict__ cnt) {
    __shared__ float sv[4][NH];
    __shared__ int sg[4];
    int wave = threadIdx.x >> 6;
    int lane = threadIdx.x & 63;
    int fq = lane & 7;        // float4 index: features 4*fq..4*fq+3
    int es = lane >> 3;       // edge slot 0..7
    int v = blockIdx.x * 4 + wave;  // NN % 4 == 0: exact
    int beg = row_ptr[v], end = row_ptr[v + 1];
    float4 acc = {0.f, 0.f, 0.f, 0.f};
    for (int i = beg + es; i < end; i += 8) {
        int u = bucket[i];
        float4 m = *(const float4*)&hs[(size_t)u * NH + fq * 4];
        acc.x += m.x; acc.y += m.y; acc.z += m.z; acc.w += m.w;
    }
#pragma unroll
    for (int m = 8; m < 64; m <<= 1) {
        acc.x += __shfl_xor(acc.x, m);
        acc.y += __shfl_xor(acc.y, m);
        acc.z += __shfl_xor(acc.z, m);
        acc.w += __shfl_xor(acc.w, m);
    }
    if (es == 0) {
        float4 h = *(const float4*)&hs[(size_t)v * NH + fq * 4];
        float dv = dinv[v];
        float4 bb = *(const float4*)&b1[fq * 4];
        float4 r;
        r.x = fmaxf((acc.x + h.x) * dv + bb.x, 0.f);
        r.y = fmaxf((acc.y + h.y) * dv + bb.y, 0.f);
        r.z = fmaxf((acc.z + h.z) * dv + bb.z, 0.f);
        r.w = fmaxf((acc.w + h.w) * dv + bb.w, 0.f);
        *(float4*)&sv[wave][fq * 4] = r;
        if (fq == 0) sg[wave] = batch[v];
    }
    __syncthreads();
    if (threadIdx.x < NH) {  // run-flush 4 consecutive nodes (batch sorted)
        int ff = threadIdx.x;
        int curg = sg[0];
        float rs = 0.f, rm = 0.f, rc = 0.f;
#pragma unroll
        for (int k = 0; k < 4; ++k) {
            int g = sg[k];
            float val = sv[k][ff];
            if (g != curg) {
                atomicAdd(&s[curg * NH + ff], rs);
                atomicMax(&mx[curg * NH + ff], __float_as_uint(rm));
                if (ff == 0) atomicAdd(&cnt[curg], rc);
                curg = g; rs = 0.f; rm = 0.f; rc = 0.f;
            }
            rs += val; rm = fmaxf(rm, val); rc += 1.f;
        }
        atomicAdd(&s[curg * NH + ff], rs);
        atomicMax(&mx[curg * NH + ff], __float_as_uint(rm));  // post-relu >= 0
        if (ff == 0) atomicAdd(&cnt[curg], rc);
    }
}

// ---------------- head: out[g] = [s, s/cnt, mx] @ Wg + bg ----------------
__global__ void k_head(const float* __restrict__ s,
                       const unsigned int* __restrict__ mx,
                       const float* __restrict__ cnt,
                       const float* __restrict__ Wg,
                       const float* __restrict__ bg,
                       float* __restrict__ out) {
    int g = blockIdx.x * blockDim.x + threadIdx.x;
    if (g >= NG) return;
    float inv = 1.0f / fmaxf(cnt[g], 1.0f);
    float accv = bg[0];
#pragma unroll 4
    for (int k = 0; k < NH; ++k) {
        float sv = s[g * NH + k];
        float mv = __uint_as_float(mx[g * NH + k]);
        accv += sv * Wg[k] + sv * inv * Wg[NH + k] + mv * Wg[2 * NH + k];
    }
    out[g] = accv;
}

extern "C" void kernel_launch(void* const* d_in, const int* in_sizes, int n_in,
                              void* d_out, int out_size, void* d_ws, size_t ws_size,
                              hipStream_t stream) {
    const float* x     = (const float*)d_in[0];
    const int*   ei    = (const int*)d_in[1];
    const int*   batch = (const int*)d_in[2];
    const float* W1    = (const float*)d_in[3];
    const float* b1    = (const float*)d_in[4];
    const float* Wg    = (const float*)d_in[5];
    const float* bg    = (const float*)d_in[6];
    float* out = (float*)d_out;

    const int* src = ei;        // edge_index[0]
    const int* dst = ei + NE;   // edge_index[1]

    // workspace layout (16B-aligned offsets); hs aliases cbucket (dead after C4)
    char* ws = (char*)d_ws;
    int*          ccnt    = (int*)(ws + 0);          // NR ints
    int*          cptr    = (int*)(ws + 3136);       // NR+1
    int*          ccur    = (int*)(ws + 6272);       // NR
    int*          row_ptr = (int*)(ws + 9408);       // NN+1
    float*        dinv    = (float*)(ws + 409424);   // NN
    int*          bucket  = (int*)(ws + 809424);     // NE
    unsigned int* cbucket = (unsigned int*)(ws + 13609424);  // NE (aliased by hs)
    float*        hs      = (float*)(ws + 13609424); // NN*NH (after C4)
    float*        s       = (float*)(ws + 26409424); // NG*NH
    unsigned int* mx      = (unsigned int*)(ws + 26474960);
    float*        cnt     = (float*)(ws + 26540496); // NG
    // total 26,542,544 B

    hipMemsetAsync(ccnt, 0, NR * sizeof(int), stream);
    hipMemsetAsync(s, 0, (size_t)NG * NH * sizeof(float), stream);
    hipMemsetAsync(mx, 0, (size_t)NG * NH * sizeof(unsigned int), stream);
    hipMemsetAsync(cnt, 0, (size_t)NG * sizeof(float), stream);

    k_ccount<<<NBE, 256, 0, stream>>>(dst, ccnt);
    k_cscan<<<1, 1024, 0, stream>>>(ccnt, cptr, ccur);
    k_cscatter<<<NBE, 256, 0, stream>>>(src, dst, ccur, cbucket);
    k_rangesort<<<NR, 256, 0, stream>>>(cptr, cbucket, row_ptr, bucket, dinv);
    k_gemm<<<NN / 32, 256, 0, stream>>>(x, W1, dinv, hs);
    k_gather_pool<<<NN / 4, 256, 0, stream>>>(row_ptr, bucket, hs, dinv, b1, batch,
                                              s, mx, cnt);
    k_head<<<(NG + 255) / 256, 256, 0, stream>>>(s, mx, cnt, Wg, bg, out);
}

// Round 10
// 223.098 us; speedup vs baseline: 7.6215x; 1.1263x over previous
//
#include <hip/hip_runtime.h>
#include <hip/hip_fp16.h>

#define NN 100000   // nodes
#define NE 3200000  // edges
#define NF 128      // in features
#define NH 32       // hidden
#define NG 512      // graphs
#define NR 782      // coarse ranges = ceil(NN/128)
#define RSZ 128     // nodes per range (dst>>7, dst&127)
#define EPB 4096    // edges per block in coarse passes
#define NBE 782     // ceil(NE/EPB)

// ---------------- C1: coarse histogram (LDS-privatized) ----------------
__global__ __launch_bounds__(256) void k_ccount(const int* __restrict__ dst,
                                                int* __restrict__ ccnt) {
    __shared__ int h[NR];
    for (int i = threadIdx.x; i < NR; i += 256) h[i] = 0;
    __syncthreads();
    int base = blockIdx.x * EPB;
    int lim = NE - base;
    const int4* d4 = (const int4*)(dst + base);
#pragma unroll
    for (int k = 0; k < 4; ++k) {
        int idx = threadIdx.x + k * 256;
        if (idx * 4 < lim) {
            int4 d = d4[idx];
            atomicAdd(&h[d.x >> 7], 1);
            atomicAdd(&h[d.y >> 7], 1);
            atomicAdd(&h[d.z >> 7], 1);
            atomicAdd(&h[d.w >> 7], 1);
        }
    }
    __syncthreads();
    for (int i = threadIdx.x; i < NR; i += 256) {
        int c = h[i];
        if (c) atomicAdd(&ccnt[i], c);
    }
}

// ---------------- C2: scan coarse counts -> cptr, ccur ----------------
__global__ __launch_bounds__(1024) void k_cscan(const int* __restrict__ ccnt,
                                                int* __restrict__ cptr,
                                                int* __restrict__ ccur) {
    int t = threadIdx.x;
    int own = (t < NR) ? ccnt[t] : 0;
    __shared__ int part[1024];
    part[t] = own;
    __syncthreads();
    for (int off = 1; off < 1024; off <<= 1) {
        int v = (t >= off) ? part[t - off] : 0;
        __syncthreads();
        part[t] += v;
        __syncthreads();
    }
    if (t < NR) { int ex = part[t] - own; cptr[t] = ex; ccur[t] = ex; }
    if (t == 0) cptr[NR] = NE;
}

// ---------------- C3: coarse scatter of packed (dstoff,src) words ----------------
__global__ __launch_bounds__(256) void k_cscatter(const int* __restrict__ src,
                                                  const int* __restrict__ dst,
                                                  int* __restrict__ ccur,
                                                  unsigned int* __restrict__ cbucket) {
    __shared__ int h[NR];
    __shared__ int basev[NR];
    for (int i = threadIdx.x; i < NR; i += 256) h[i] = 0;
    __syncthreads();
    int base = blockIdx.x * EPB;
    int lim = NE - base;
    const int4* d4 = (const int4*)(dst + base);
    const int4* s4 = (const int4*)(src + base);
    int4 dv[4], sv[4];
    int valid[4];
#pragma unroll
    for (int k = 0; k < 4; ++k) {
        int idx = threadIdx.x + k * 256;
        valid[k] = (idx * 4 < lim);
        if (valid[k]) {
            dv[k] = d4[idx];
            sv[k] = s4[idx];
            atomicAdd(&h[dv[k].x >> 7], 1);
            atomicAdd(&h[dv[k].y >> 7], 1);
            atomicAdd(&h[dv[k].z >> 7], 1);
            atomicAdd(&h[dv[k].w >> 7], 1);
        }
    }
    __syncthreads();
    for (int i = threadIdx.x; i < NR; i += 256) {   // reserve global bases
        int c = h[i];
        basev[i] = c ? atomicAdd(&ccur[i], c) : 0;
    }
    __syncthreads();
    for (int i = threadIdx.x; i < NR; i += 256) h[i] = 0;  // reuse as rank counters
    __syncthreads();
#pragma unroll
    for (int k = 0; k < 4; ++k) {
        if (valid[k]) {
            int d, s, r, p;
#define EMIT(DD, SS) d = (DD); s = (SS); r = d >> 7; \
            p = basev[r] + atomicAdd(&h[r], 1); \
            cbucket[p] = (unsigned int)(((d & 127) << 17) | s);
            EMIT(dv[k].x, sv[k].x)
            EMIT(dv[k].y, sv[k].y)
            EMIT(dv[k].z, sv[k].z)
            EMIT(dv[k].w, sv[k].w)
#undef EMIT
        }
    }
}

// ---------------- C4: per-range local sort -> bucket, row_ptr, dinv ----------------
__global__ __launch_bounds__(256) void k_rangesort(const int* __restrict__ cptr,
                                                   const unsigned int* __restrict__ cbucket,
                                                   int* __restrict__ row_ptr,
                                                   int* __restrict__ bucket,
                                                   float* __restrict__ dinv) {
    __shared__ int h[RSZ];
    __shared__ int lptr[RSZ];
    int r = blockIdx.x;
    int beg = cptr[r], end = cptr[r + 1];
    int t = threadIdx.x;
    if (t < RSZ) h[t] = 0;
    __syncthreads();
    for (int i = beg + t; i < end; i += 256)
        atomicAdd(&h[cbucket[i] >> 17], 1);
    __syncthreads();
    if (t < RSZ) lptr[t] = h[t];
    __syncthreads();
    for (int off = 1; off < RSZ; off <<= 1) {      // inclusive scan over 128
        int v = (t >= off && t < RSZ) ? lptr[t - off] : 0;
        __syncthreads();
        if (t < RSZ) lptr[t] += v;
        __syncthreads();
    }
    int node0 = r * RSZ;
    if (t < RSZ) {
        int v = node0 + t;
        if (v < NN) {
            int ex = lptr[t] - h[t];               // exclusive
            row_ptr[v] = beg + ex;
            dinv[v] = rsqrtf((float)(h[t] + 1));   // +1 self-loop
        }
    }
    __syncthreads();
    if (t < RSZ) h[t] = lptr[t] - h[t];            // reuse h as LDS cursor
    __syncthreads();
    for (int i = beg + t; i < end; i += 256) {
        unsigned int w = cbucket[i];
        int off_ = atomicAdd(&h[w >> 17], 1);
        bucket[beg + off_] = (int)(w & 0x1FFFF);
    }
    if (r == 0 && t == 0) row_ptr[NN] = NE;
}

// ---------------- hs(fp16) = (x @ W1) * dinv[row] ----------------
__global__ __launch_bounds__(256) void k_gemm(const float* __restrict__ x,
                                              const float* __restrict__ W1,
                                              const float* __restrict__ dinv,
                                              __half* __restrict__ hs) {
    __shared__ float sW[NF][NH];        // 16 KB
    __shared__ float sX[32][NF + 4];    // padded: no bank conflict
    int t = threadIdx.x;
    const float4* W4 = (const float4*)W1;
    float4* sW4 = (float4*)&sW[0][0];
#pragma unroll
    for (int i = 0; i < 4; ++i) sW4[t + 256 * i] = W4[t + 256 * i];

    long row0 = (long)blockIdx.x * 32;
    const float4* x4 = (const float4*)(x + row0 * NF);
#pragma unroll
    for (int i = 0; i < 4; ++i) {
        int idx4 = t + 256 * i;
        int r = idx4 >> 5;
        int c = (idx4 & 31) * 4;
        float4 v = x4[idx4];
        sX[r][c] = v.x; sX[r][c + 1] = v.y; sX[r][c + 2] = v.z; sX[r][c + 3] = v.w;
    }
    __syncthreads();

    int r = t >> 3;
    int c = (t & 7) * 4;
    float4 acc = {0.f, 0.f, 0.f, 0.f};
#pragma unroll 8
    for (int k = 0; k < NF; ++k) {
        float xv = sX[r][k];
        float4 w = *(const float4*)&sW[k][c];
        acc.x += xv * w.x; acc.y += xv * w.y;
        acc.z += xv * w.z; acc.w += xv * w.w;
    }
    float dv = dinv[row0 + r];
    __half2 h01 = __floats2half2_rn(acc.x * dv, acc.y * dv);
    __half2 h23 = __floats2half2_rn(acc.z * dv, acc.w * dv);
    uint2 packed = { *(unsigned int*)&h01, *(unsigned int*)&h23 };
    *(uint2*)&hs[(row0 + r) * NH + c] = packed;   // 8B store, aligned
}

// ---------------- gather + finalize + fused pooling (fp16 hs) ----------------
// 1 wave per node (4 nodes/block). lane = es*4 + fq: es in [0,16) edge slots,
// fq in [0,4) 16B chunks -> 16 edges x 16B (8 halves) in flight per iteration.
__global__ __launch_bounds__(256) void k_gather_pool(
    const int* __restrict__ row_ptr, const int* __restrict__ bucket,
    const __half* __restrict__ hs, const float* __restrict__ dinv,
    const float* __restrict__ b1, const int* __restrict__ batch,
    float* __restrict__ s, unsigned int* __restrict__ mx, float* __restrict__ cnt) {
    __shared__ __align__(16) float sv[4][NH];
    __shared__ int sg[4];
    int wave = threadIdx.x >> 6;
    int lane = threadIdx.x & 63;
    int fq = lane & 3;        // 16B chunk: halves 8*fq..8*fq+7
    int es = lane >> 2;       // edge slot 0..15
    int v = blockIdx.x * 4 + wave;  // NN % 4 == 0: exact
    int beg = row_ptr[v], end = row_ptr[v + 1];
    float4 a0 = {0.f, 0.f, 0.f, 0.f};
    float4 a1 = {0.f, 0.f, 0.f, 0.f};
    for (int i = beg + es; i < end; i += 16) {
        int u = bucket[i];
        uint4 raw = *(const uint4*)&hs[(size_t)u * NH + fq * 8];  // 16B; 64B/edge
        float2 f0 = __half22float2(*(__half2*)&raw.x);
        float2 f1 = __half22float2(*(__half2*)&raw.y);
        float2 f2 = __half22float2(*(__half2*)&raw.z);
        float2 f3 = __half22float2(*(__half2*)&raw.w);
        a0.x += f0.x; a0.y += f0.y; a0.z += f1.x; a0.w += f1.y;
        a1.x += f2.x; a1.y += f2.y; a1.z += f3.x; a1.w += f3.y;
    }
#pragma unroll
    for (int m = 4; m < 64; m <<= 1) {  // reduce across es (4 steps)
        a0.x += __shfl_xor(a0.x, m); a0.y += __shfl_xor(a0.y, m);
        a0.z += __shfl_xor(a0.z, m); a0.w += __shfl_xor(a0.w, m);
        a1.x += __shfl_xor(a1.x, m); a1.y += __shfl_xor(a1.y, m);
        a1.z += __shfl_xor(a1.z, m); a1.w += __shfl_xor(a1.w, m);
    }
    if (es == 0) {
        uint4 raw = *(const uint4*)&hs[(size_t)v * NH + fq * 8];  // self-loop
        float2 f0 = __half22float2(*(__half2*)&raw.x);
        float2 f1 = __half22float2(*(__half2*)&raw.y);
        float2 f2 = __half22float2(*(__half2*)&raw.z);
        float2 f3 = __half22float2(*(__half2*)&raw.w);
        float dv = dinv[v];
        float4 bb0 = *(const float4*)&b1[fq * 8];
        float4 bb1 = *(const float4*)&b1[fq * 8 + 4];
        float4 r0, r1;
        r0.x = fmaxf((a0.x + f0.x) * dv + bb0.x, 0.f);
        r0.y = fmaxf((a0.y + f0.y) * dv + bb0.y, 0.f);
        r0.z = fmaxf((a0.z + f1.x) * dv + bb0.z, 0.f);
        r0.w = fmaxf((a0.w + f1.y) * dv + bb0.w, 0.f);
        r1.x = fmaxf((a1.x + f2.x) * dv + bb1.x, 0.f);
        r1.y = fmaxf((a1.y + f2.y) * dv + bb1.y, 0.f);
        r1.z = fmaxf((a1.z + f3.x) * dv + bb1.z, 0.f);
        r1.w = fmaxf((a1.w + f3.y) * dv + bb1.w, 0.f);
        *(float4*)&sv[wave][fq * 8] = r0;
        *(float4*)&sv[wave][fq * 8 + 4] = r1;
        if (fq == 0) sg[wave] = batch[v];
    }
    __syncthreads();
    if (threadIdx.x < NH) {  // run-flush 4 consecutive nodes (batch sorted)
        int ff = threadIdx.x;
        int curg = sg[0];
        float rs = 0.f, rm = 0.f, rc = 0.f;
#pragma unroll
        for (int k = 0; k < 4; ++k) {
            int g = sg[k];
            float val = sv[k][ff];
            if (g != curg) {
                atomicAdd(&s[curg * NH + ff], rs);
                atomicMax(&mx[curg * NH + ff], __float_as_uint(rm));
                if (ff == 0) atomicAdd(&cnt[curg], rc);
                curg = g; rs = 0.f; rm = 0.f; rc = 0.f;
            }
            rs += val; rm = fmaxf(rm, val); rc += 1.f;
        }
        atomicAdd(&s[curg * NH + ff], rs);
        atomicMax(&mx[curg * NH + ff], __float_as_uint(rm));  // post-relu >= 0
        if (ff == 0) atomicAdd(&cnt[curg], rc);
    }
}

// ---------------- head: out[g] = [s, s/cnt, mx] @ Wg + bg ----------------
__global__ void k_head(const float* __restrict__ s,
                       const unsigned int* __restrict__ mx,
                       const float* __restrict__ cnt,
                       const float* __restrict__ Wg,
                       const float* __restrict__ bg,
                       float* __restrict__ out) {
    int g = blockIdx.x * blockDim.x + threadIdx.x;
    if (g >= NG) return;
    float inv = 1.0f / fmaxf(cnt[g], 1.0f);
    float accv = bg[0];
#pragma unroll 4
    for (int k = 0; k < NH; ++k) {
        float sv = s[g * NH + k];
        float mv = __uint_as_float(mx[g * NH + k]);
        accv += sv * Wg[k] + sv * inv * Wg[NH + k] + mv * Wg[2 * NH + k];
    }
    out[g] = accv;
}

extern "C" void kernel_launch(void* const* d_in, const int* in_sizes, int n_in,
                              void* d_out, int out_size, void* d_ws, size_t ws_size,
                              hipStream_t stream) {
    const float* x     = (const float*)d_in[0];
    const int*   ei    = (const int*)d_in[1];
    const int*   batch = (const int*)d_in[2];
    const float* W1    = (const float*)d_in[3];
    const float* b1    = (const float*)d_in[4];
    const float* Wg    = (const float*)d_in[5];
    const float* bg    = (const float*)d_in[6];
    float* out = (float*)d_out;

    const int* src = ei;        // edge_index[0]
    const int* dst = ei + NE;   // edge_index[1]

    // workspace layout (16B-aligned offsets); hs(fp16) aliases cbucket (dead after C4)
    char* ws = (char*)d_ws;
    int*          ccnt    = (int*)(ws + 0);          // NR ints
    int*          cptr    = (int*)(ws + 3136);       // NR+1
    int*          ccur    = (int*)(ws + 6272);       // NR
    int*          row_ptr = (int*)(ws + 9408);       // NN+1
    float*        dinv    = (float*)(ws + 409424);   // NN
    int*          bucket  = (int*)(ws + 809424);     // NE
    unsigned int* cbucket = (unsigned int*)(ws + 13609424);  // NE (aliased by hs)
    __half*       hs      = (__half*)(ws + 13609424);// NN*NH fp16 (after C4)
    float*        s       = (float*)(ws + 26409424); // NG*NH
    unsigned int* mx      = (unsigned int*)(ws + 26474960);
    float*        cnt     = (float*)(ws + 26540496); // NG
    // total 26,542,544 B

    hipMemsetAsync(ccnt, 0, NR * sizeof(int), stream);
    hipMemsetAsync(s, 0, (size_t)NG * NH * sizeof(float), stream);
    hipMemsetAsync(mx, 0, (size_t)NG * NH * sizeof(unsigned int), stream);
    hipMemsetAsync(cnt, 0, (size_t)NG * sizeof(float), stream);

    k_ccount<<<NBE, 256, 0, stream>>>(dst, ccnt);
    k_cscan<<<1, 1024, 0, stream>>>(ccnt, cptr, ccur);
    k_cscatter<<<NBE, 256, 0, stream>>>(src, dst, ccur, cbucket);
    k_rangesort<<<NR, 256, 0, stream>>>(cptr, cbucket, row_ptr, bucket, dinv);
    k_gemm<<<NN / 32, 256, 0, stream>>>(x, W1, dinv, hs);
    k_gather_pool<<<NN / 4, 256, 0, stream>>>(row_ptr, bucket, hs, dinv, b1, batch,
                                              s, mx, cnt);
    k_head<<<(NG + 255) / 256, 256, 0, stream>>>(s, mx, cnt, Wg, bg, out);
}